// Round 8
// baseline (270.136 us; speedup 1.0000x reference)
//
#include <hip/hip_runtime.h>
#include <hip/hip_bf16.h>

// Conv_SelfAttn — B=8, C=128, N=4096, C_QK=16. fp32 in/out.
// Round 8: kill spills + deep pipeline.
//  - launch_bounds(256,2): grid 512 = 2 blocks/CU (grid-limited), so a 3-block
//    reg cap (r7) only caused spills -> 333 MB HBM write-evictions. 256-reg
//    budget fits the whole working set.
//  - vT double-buffered [kq][buf][c][m] (74 KB) -> ONE barrier/iter.
//  - K frags pipelined one iter ahead in regs (clamped addr, branchless).
//  - flat 64-key iteration: s1 MFMAs overlap s0 exp chain.
// Math identical to r6/r7 (no-max exp2 softmax, log2e folded into Wq).
// Layouts (32x32x16_bf16), validated rounds 4-7:
//   C/D: col=lane&31, row=(reg&3)+8*(reg>>2)+4*(lane>>5)
//   A  : m=lane&31,  k=8*(lane>>5)+j
//   B  : n=lane&31,  k=8*(lane>>5)+j
// ws: qw fp32 [B][N][16] (x log2e) | khw bf16 [B][N][16] | klw bf16 [B][N][16]
//     | vw bf16 [B][C][N] (V^T)

typedef __bf16 bf16x8 __attribute__((ext_vector_type(8)));
typedef __bf16 bf16x4 __attribute__((ext_vector_type(4)));
typedef float  f32x16 __attribute__((ext_vector_type(16)));
typedef unsigned int u32;
typedef u32 u32x4 __attribute__((ext_vector_type(4)));

static constexpr int Bb = 8, Cc = 128, Nn = 4096, CQ = 16;
static constexpr float LOG2E = 1.44269504088896f;

__device__ __forceinline__ f32x16 mfma32(bf16x8 a, bf16x8 b, f32x16 c) {
    return __builtin_amdgcn_mfma_f32_32x32x16_bf16(a, b, c, 0, 0, 0);
}
struct HL { __bf16 h, l; };
__device__ __forceinline__ HL hilo(float f) {
    HL r;
    r.h = (__bf16)f;
    r.l = (__bf16)(f - (float)r.h);
    return r;
}
__device__ __forceinline__ u32 pack2(float a, float b) {
    unsigned short ua = __builtin_bit_cast(unsigned short, (__bf16)a);
    unsigned short ub = __builtin_bit_cast(unsigned short, (__bf16)b);
    return (u32)ua | ((u32)ub << 16);
}

// ---------------- Kernel 1: QKV projection (MFMA) — as rounds 6/7 ------------
__global__ __launch_bounds__(256) void qkv_kernel(
    const float* __restrict__ x, const float* __restrict__ Wq,
    const float* __restrict__ Wk, const float* __restrict__ Wv,
    float* __restrict__ qw, __bf16* __restrict__ khw, __bf16* __restrict__ klw,
    __bf16* __restrict__ vw)
{
    const int b = blockIdx.y, n0 = blockIdx.x * 64, t = threadIdx.x;
    const int wave = t >> 6, lane = t & 63, lr = lane & 31, lq = lane >> 5;

    __shared__ __bf16 xh[64][136], xl[64][136];
    __shared__ __bf16 wqh[32][136], wql[32][136];
    __shared__ __bf16 wvh[128][136];

    {
        const int n = t & 63, cib = t >> 6;
        #pragma unroll 4
        for (int i = 0; i < 32; ++i) {
            int ci = cib + i * 4;
            float v = x[((size_t)(b * Cc + ci)) * Nn + n0 + n];
            HL z = hilo(v);
            xh[n][ci] = z.h; xl[n][ci] = z.l;
        }
    }
    #pragma unroll
    for (int i = 0; i < 8; ++i) {
        int idx = t + i * 256;
        int o = idx >> 7, ci = idx & 127;
        HL zq = hilo(Wq[idx] * LOG2E);      // fold log2e into Q
        wqh[o][ci] = zq.h; wql[o][ci] = zq.l;
        HL zk = hilo(Wk[idx]);
        wqh[16 + o][ci] = zk.h; wql[16 + o][ci] = zk.l;
    }
    #pragma unroll
    for (int i = 0; i < 16; ++i) {
        int flat = t * 4 + i * 1024;
        float4 w4 = *(const float4*)(Wv + flat);
        int c = flat >> 7, ci0 = flat & 127;
        bf16x4 h4 = { (__bf16)w4.x, (__bf16)w4.y, (__bf16)w4.z, (__bf16)w4.w };
        *(bf16x4*)&wvh[c][ci0] = h4;
    }
    __syncthreads();

    if (wave < 2) {
        const int nh = wave;
        f32x16 acc = {};
        #pragma unroll
        for (int ks = 0; ks < 8; ++ks) {
            bf16x8 ah = *(const bf16x8*)&wqh[lr][ks * 16 + lq * 8];
            bf16x8 al = *(const bf16x8*)&wql[lr][ks * 16 + lq * 8];
            bf16x8 bh = *(const bf16x8*)&xh[nh * 32 + lr][ks * 16 + lq * 8];
            bf16x8 bl = *(const bf16x8*)&xl[nh * 32 + lr][ks * 16 + lq * 8];
            acc = mfma32(ah, bh, acc);
            acc = mfma32(al, bh, acc);
            acc = mfma32(ah, bl, acc);
        }
        const int n = n0 + nh * 32 + lr;
        #pragma unroll
        for (int r = 0; r < 16; ++r) {
            int op = (r & 3) + 8 * (r >> 2) + 4 * lq;
            if (op < 16) qw[((size_t)(b * Nn + n)) * CQ + op] = acc[r];
            else {
                HL z = hilo(acc[r]);
                khw[((size_t)(b * Nn + n)) * CQ + (op - 16)] = z.h;
                klw[((size_t)(b * Nn + n)) * CQ + (op - 16)] = z.l;
            }
        }
    }
    {
        int tl[3][2]; int nt;
        if      (wave == 0) { tl[0][0]=2; tl[0][1]=0; nt=1; }
        else if (wave == 1) { tl[0][0]=2; tl[0][1]=1; nt=1; }
        else if (wave == 2) { tl[0][0]=0; tl[0][1]=0; tl[1][0]=1; tl[1][1]=0; tl[2][0]=3; tl[2][1]=0; nt=3; }
        else                { tl[0][0]=0; tl[0][1]=1; tl[1][0]=1; tl[1][1]=1; tl[2][0]=3; tl[2][1]=1; nt=3; }
        for (int ti = 0; ti < nt; ++ti) {
            const int ct = tl[ti][0], nh = tl[ti][1];
            f32x16 acc = {};
            #pragma unroll
            for (int ks = 0; ks < 8; ++ks) {
                bf16x8 a  = *(const bf16x8*)&wvh[ct * 32 + lr][ks * 16 + lq * 8];
                bf16x8 bh = *(const bf16x8*)&xh[nh * 32 + lr][ks * 16 + lq * 8];
                acc = mfma32(a, bh, acc);
            }
            const int n = n0 + nh * 32 + lr;
            #pragma unroll
            for (int r = 0; r < 16; ++r) {
                int c = (r & 3) + 8 * (r >> 2) + 4 * lq + ct * 32;
                vw[((size_t)(b * Cc + c)) * Nn + n] = (__bf16)acc[r];
            }
        }
    }
}

// ------ Kernel 2: attention, 4 waves = 2 qg x 2 key-halves, q-tile 64 --------
// grid (64, 8), 256 threads, 2 blocks/CU, 1 barrier/iter.
__global__ __launch_bounds__(256, 2) void attn_kernel(
    const float* __restrict__ x, const float* __restrict__ qw,
    const __bf16* __restrict__ khw, const __bf16* __restrict__ klw,
    const __bf16* __restrict__ vw,
    const float* __restrict__ gamma, float* __restrict__ out)
{
    const int b = blockIdx.y, n0b = blockIdx.x * 64, t = threadIdx.x;
    const int wave = t >> 6, lane = t & 63, lr = lane & 31, lq = lane >> 5;
    const int qg = wave & 1, kq = wave >> 1;
    const int kbase = kq * 2048;

    // [kq-half][buf][c][m] bf16, 73728 B; merge region reuses it at the end.
    __shared__ __align__(16) unsigned char smem[2 * 2 * 128 * 72 * 2];
    __shared__ float lred[2][32];
    __bf16 (*vT)[2][128][72] = (__bf16 (*)[2][128][72])smem;

    // staging map (measured 0 LDS conflicts in r5/r7): pair-per-row
    const int sc = t >> 1, sm = (t & 1) * 32;
    const __bf16* vbase = vw + ((size_t)(b * Cc + sc)) * Nn + sm;

    // Q frags (qw pre-scaled by log2e)
    const int nq = n0b + qg * 32 + lr;
    bf16x8 qhi, qlo;
    {
        float qa[8];
        *(float4*)&qa[0] = *(const float4*)(qw + ((size_t)b * Nn + nq) * CQ + lq * 8);
        *(float4*)&qa[4] = *(const float4*)(qw + ((size_t)b * Nn + nq) * CQ + lq * 8 + 4);
        #pragma unroll
        for (int j = 0; j < 8; ++j) { HL z = hilo(qa[j]); qhi[j] = z.h; qlo[j] = z.l; }
    }

    const __bf16* khb = khw + ((size_t)b * Nn + kbase) * CQ + lq * 8;
    const __bf16* klb = klw + ((size_t)b * Nn + kbase) * CQ + lq * 8;

    // ---- prologue: stage chunk 0 -> buf 0; prefetch chunk 1; K(0) in regs ----
    uint4 pv[2][4];
    #pragma unroll
    for (int h = 0; h < 2; ++h)
        #pragma unroll
        for (int i = 0; i < 4; ++i) pv[h][i] = *(const uint4*)(vbase + h * 2048 + 8 * i);
    #pragma unroll
    for (int h = 0; h < 2; ++h)
        #pragma unroll
        for (int i = 0; i < 4; ++i) *(uint4*)&vT[h][0][sc][sm + 8 * i] = pv[h][i];
    #pragma unroll
    for (int h = 0; h < 2; ++h)
        #pragma unroll
        for (int i = 0; i < 4; ++i) pv[h][i] = *(const uint4*)(vbase + h * 2048 + 64 + 8 * i);

    bf16x8 k0h = *(const bf16x8*)(khb + (size_t)lr * CQ);
    bf16x8 k0l = *(const bf16x8*)(klb + (size_t)lr * CQ);
    bf16x8 k1h = *(const bf16x8*)(khb + (size_t)(32 + lr) * CQ);
    bf16x8 k1l = *(const bf16x8*)(klb + (size_t)(32 + lr) * CQ);

    __syncthreads();

    f32x16 acc[4] = {{}, {}, {}, {}};
    float l_run = 0.f;

    for (int it = 0; it < 32; ++it) {
        const int p = it & 1;

        // commit staged V(it+1) -> idle buffer (readers are past last barrier)
        if (it + 1 < 32) {
            #pragma unroll
            for (int h = 0; h < 2; ++h)
                #pragma unroll
                for (int i = 0; i < 4; ++i)
                    *(uint4*)&vT[h][1 - p][sc][sm + 8 * i] = pv[h][i];
        }
        // prefetch V(it+2) into regs (clamped, branchless)
        {
            const int nc = (it + 2 < 32) ? it + 2 : 31;
            #pragma unroll
            for (int h = 0; h < 2; ++h)
                #pragma unroll
                for (int i = 0; i < 4; ++i)
                    pv[h][i] = *(const uint4*)(vbase + h * 2048 + nc * 64 + 8 * i);
        }

        // S^T = K * Q^T for 64 keys (current K regs)
        f32x16 s0 = {}, s1 = {};
        s0 = mfma32(k0h, qhi, s0); s0 = mfma32(k0l, qhi, s0); s0 = mfma32(k0h, qlo, s0);
        s1 = mfma32(k1h, qhi, s1); s1 = mfma32(k1l, qhi, s1); s1 = mfma32(k1h, qlo, s1);

        // prefetch K(it+1) (clamped)
        {
            const int nit = (it + 1 < 32) ? it + 1 : 31;
            const size_t r0 = (size_t)(nit * 64 + lr) * CQ;
            const size_t r1 = (size_t)(nit * 64 + 32 + lr) * CQ;
            bf16x8 nk0h = *(const bf16x8*)(khb + r0);
            bf16x8 nk0l = *(const bf16x8*)(klb + r0);
            bf16x8 nk1h = *(const bf16x8*)(khb + r1);
            bf16x8 nk1l = *(const bf16x8*)(klb + r1);

            // no-max softmax: p = exp2(s) (s already includes log2e)
            u32 Qk[16];
            float csum = 0.f;
            #pragma unroll
            for (int g = 0; g < 4; ++g) {
                float a = __builtin_exp2f(s0[4*g]),   bq = __builtin_exp2f(s0[4*g+1]);
                float c = __builtin_exp2f(s0[4*g+2]), d  = __builtin_exp2f(s0[4*g+3]);
                csum += (a + bq) + (c + d);
                Qk[2*g] = pack2(a, bq); Qk[2*g+1] = pack2(c, d);
            }
            #pragma unroll
            for (int g = 0; g < 4; ++g) {
                float a = __builtin_exp2f(s1[4*g]),   bq = __builtin_exp2f(s1[4*g+1]);
                float c = __builtin_exp2f(s1[4*g+2]), d  = __builtin_exp2f(s1[4*g+3]);
                csum += (a + bq) + (c + d);
                Qk[8+2*g] = pack2(a, bq); Qk[8+2*g+1] = pack2(c, d);
            }
            l_run += csum;

            // exchange quads with xor-32 partner; build P B-frags (r4-r7 formula)
            u32 Sh[16];
            #pragma unroll
            for (int i = 0; i < 16; ++i) Sh[i] = (u32)__shfl_xor((int)Qk[i], 32);
            bf16x8 pf[4];
            #pragma unroll
            for (int ks = 0; ks < 4; ++ks) {
                int z = 2 * ks + lq, base = (z >> 2) * 8 + (z & 3) * 2;
                u32x4 w;
                if (lq == 0) { w[0] = Qk[base]; w[1] = Qk[base + 1]; w[2] = Sh[base]; w[3] = Sh[base + 1]; }
                else         { w[0] = Sh[base]; w[1] = Sh[base + 1]; w[2] = Qk[base]; w[3] = Qk[base + 1]; }
                pf[ks] = __builtin_bit_cast(bf16x8, w);
            }

            // O^T += V^T * P  (reads current buffer p)
            #pragma unroll
            for (int ct = 0; ct < 4; ++ct) {
                #pragma unroll
                for (int ks = 0; ks < 4; ++ks) {
                    bf16x8 va = *(const bf16x8*)&vT[kq][p][ct * 32 + lr][ks * 16 + lq * 8];
                    acc[ct] = mfma32(va, pf[ks], acc[ct]);
                }
            }

            // rotate K pipeline
            k0h = nk0h; k0l = nk0l; k1h = nk1h; k1l = nk1l;
        }

        __syncthreads();   // the only barrier per iteration
    }

    // ---- additive merge across the two key-halves (no-max => plain sums) ----
    const float l_tot = l_run + __shfl_xor(l_run, 32);
    constexpr int RP = 129;
    float* mergeO = (float*)smem;            // vT dead; reuse
    float* reg = mergeO + qg * (32 * RP);

    if (kq == 1) {
        if (lq == 0) lred[qg][lr] = l_tot;
        #pragma unroll
        for (int ct = 0; ct < 4; ++ct)
            #pragma unroll
            for (int r = 0; r < 16; ++r) {
                int c = (r & 3) + 8 * (r >> 2) + 4 * lq + 32 * ct;
                reg[lr * RP + c] = acc[ct][r];
            }
    }
    __syncthreads();
    if (kq == 0) {
        const float linv = 1.0f / (l_tot + lred[qg][lr]);
        const float gg = gamma[0];
        #pragma unroll
        for (int ct = 0; ct < 4; ++ct)
            #pragma unroll
            for (int r = 0; r < 16; ++r) {
                int c = (r & 3) + 8 * (r >> 2) + 4 * lq + 32 * ct;
                size_t idx = ((size_t)(b * Cc + c)) * Nn + nq;
                out[idx] = x[idx] + gg * (acc[ct][r] + reg[lr * RP + c]) * linv;
            }
    }
}

extern "C" void kernel_launch(void* const* d_in, const int* in_sizes, int n_in,
                              void* d_out, int out_size, void* d_ws, size_t ws_size,
                              hipStream_t stream) {
    const float* x  = (const float*)d_in[0];
    const float* Wq = (const float*)d_in[1];
    const float* Wk = (const float*)d_in[2];
    const float* Wv = (const float*)d_in[3];
    const float* gm = (const float*)d_in[4];

    float*  qw  = (float*)d_ws;                               // [B][N][16] fp32 (x log2e)
    __bf16* khw = (__bf16*)(qw + (size_t)Bb * Nn * CQ);       // [B][N][16] bf16 hi
    __bf16* klw = khw + (size_t)Bb * Nn * CQ;                 // [B][N][16] bf16 lo
    __bf16* vw  = klw + (size_t)Bb * Nn * CQ;                 // [B][C][N] bf16 (V^T)

    qkv_kernel<<<dim3(Nn / 64, Bb), 256, 0, stream>>>(x, Wq, Wk, Wv, qw, khw, klw, vw);
    attn_kernel<<<dim3(Nn / 64, Bb), 256, 0, stream>>>(x, qw, khw, klw, vw, gm,
                                                       (float*)d_out);
}

// Round 9
// 251.818 us; speedup vs baseline: 1.0727x; 1.0727x over previous
//
#include <hip/hip_runtime.h>
#include <hip/hip_bf16.h>

// Conv_SelfAttn — B=8, C=128, N=4096, C_QK=16. fp32 in/out.
// Round 9: eliminate scratch traffic. r7/r8 WRITE_SIZE ~320-330 MB was NOT a
// launch-bounds issue (r8 had 80 regs headroom): the P-frag build indexed
// private arrays Qk[]/Sh[] with a runtime value (base = f(lq)) — under
// pressure LLVM demotes such arrays to scratch. This round: all private-array
// indices are compile-time constants; lq-dependence moved into value selects
// (?: -> v_cndmask), and the quad exchange sends pre-selected payloads so only
// 8 shfl_xor are needed (was 16).
// Everything else identical to round 8 (1 barrier/iter, dbuf vT, K pipelined).
// Layouts (32x32x16_bf16), validated rounds 4-8:
//   C/D: col=lane&31, row=(reg&3)+8*(reg>>2)+4*(lane>>5)
//   A  : m=lane&31,  k=8*(lane>>5)+j
//   B  : n=lane&31,  k=8*(lane>>5)+j
// ws: qw fp32 [B][N][16] (x log2e) | khw bf16 [B][N][16] | klw bf16 [B][N][16]
//     | vw bf16 [B][C][N] (V^T)

typedef __bf16 bf16x8 __attribute__((ext_vector_type(8)));
typedef __bf16 bf16x4 __attribute__((ext_vector_type(4)));
typedef float  f32x16 __attribute__((ext_vector_type(16)));
typedef unsigned int u32;
typedef u32 u32x4 __attribute__((ext_vector_type(4)));

static constexpr int Bb = 8, Cc = 128, Nn = 4096, CQ = 16;
static constexpr float LOG2E = 1.44269504088896f;

__device__ __forceinline__ f32x16 mfma32(bf16x8 a, bf16x8 b, f32x16 c) {
    return __builtin_amdgcn_mfma_f32_32x32x16_bf16(a, b, c, 0, 0, 0);
}
struct HL { __bf16 h, l; };
__device__ __forceinline__ HL hilo(float f) {
    HL r;
    r.h = (__bf16)f;
    r.l = (__bf16)(f - (float)r.h);
    return r;
}
__device__ __forceinline__ u32 pack2(float a, float b) {
    unsigned short ua = __builtin_bit_cast(unsigned short, (__bf16)a);
    unsigned short ub = __builtin_bit_cast(unsigned short, (__bf16)b);
    return (u32)ua | ((u32)ub << 16);
}

// ---------------- Kernel 1: QKV projection (MFMA) — as rounds 6-8 ------------
__global__ __launch_bounds__(256) void qkv_kernel(
    const float* __restrict__ x, const float* __restrict__ Wq,
    const float* __restrict__ Wk, const float* __restrict__ Wv,
    float* __restrict__ qw, __bf16* __restrict__ khw, __bf16* __restrict__ klw,
    __bf16* __restrict__ vw)
{
    const int b = blockIdx.y, n0 = blockIdx.x * 64, t = threadIdx.x;
    const int wave = t >> 6, lane = t & 63, lr = lane & 31, lq = lane >> 5;

    __shared__ __bf16 xh[64][136], xl[64][136];
    __shared__ __bf16 wqh[32][136], wql[32][136];
    __shared__ __bf16 wvh[128][136];

    {
        const int n = t & 63, cib = t >> 6;
        #pragma unroll 4
        for (int i = 0; i < 32; ++i) {
            int ci = cib + i * 4;
            float v = x[((size_t)(b * Cc + ci)) * Nn + n0 + n];
            HL z = hilo(v);
            xh[n][ci] = z.h; xl[n][ci] = z.l;
        }
    }
    #pragma unroll
    for (int i = 0; i < 8; ++i) {
        int idx = t + i * 256;
        int o = idx >> 7, ci = idx & 127;
        HL zq = hilo(Wq[idx] * LOG2E);      // fold log2e into Q
        wqh[o][ci] = zq.h; wql[o][ci] = zq.l;
        HL zk = hilo(Wk[idx]);
        wqh[16 + o][ci] = zk.h; wql[16 + o][ci] = zk.l;
    }
    #pragma unroll
    for (int i = 0; i < 16; ++i) {
        int flat = t * 4 + i * 1024;
        float4 w4 = *(const float4*)(Wv + flat);
        int c = flat >> 7, ci0 = flat & 127;
        bf16x4 h4 = { (__bf16)w4.x, (__bf16)w4.y, (__bf16)w4.z, (__bf16)w4.w };
        *(bf16x4*)&wvh[c][ci0] = h4;
    }
    __syncthreads();

    if (wave < 2) {
        const int nh = wave;
        f32x16 acc = {};
        #pragma unroll
        for (int ks = 0; ks < 8; ++ks) {
            bf16x8 ah = *(const bf16x8*)&wqh[lr][ks * 16 + lq * 8];
            bf16x8 al = *(const bf16x8*)&wql[lr][ks * 16 + lq * 8];
            bf16x8 bh = *(const bf16x8*)&xh[nh * 32 + lr][ks * 16 + lq * 8];
            bf16x8 bl = *(const bf16x8*)&xl[nh * 32 + lr][ks * 16 + lq * 8];
            acc = mfma32(ah, bh, acc);
            acc = mfma32(al, bh, acc);
            acc = mfma32(ah, bl, acc);
        }
        const int n = n0 + nh * 32 + lr;
        #pragma unroll
        for (int r = 0; r < 16; ++r) {
            int op = (r & 3) + 8 * (r >> 2) + 4 * lq;
            if (op < 16) qw[((size_t)(b * Nn + n)) * CQ + op] = acc[r];
            else {
                HL z = hilo(acc[r]);
                khw[((size_t)(b * Nn + n)) * CQ + (op - 16)] = z.h;
                klw[((size_t)(b * Nn + n)) * CQ + (op - 16)] = z.l;
            }
        }
    }
    {
        int tl[3][2]; int nt;
        if      (wave == 0) { tl[0][0]=2; tl[0][1]=0; nt=1; }
        else if (wave == 1) { tl[0][0]=2; tl[0][1]=1; nt=1; }
        else if (wave == 2) { tl[0][0]=0; tl[0][1]=0; tl[1][0]=1; tl[1][1]=0; tl[2][0]=3; tl[2][1]=0; nt=3; }
        else                { tl[0][0]=0; tl[0][1]=1; tl[1][0]=1; tl[1][1]=1; tl[2][0]=3; tl[2][1]=1; nt=3; }
        for (int ti = 0; ti < nt; ++ti) {
            const int ct = tl[ti][0], nh = tl[ti][1];
            f32x16 acc = {};
            #pragma unroll
            for (int ks = 0; ks < 8; ++ks) {
                bf16x8 a  = *(const bf16x8*)&wvh[ct * 32 + lr][ks * 16 + lq * 8];
                bf16x8 bh = *(const bf16x8*)&xh[nh * 32 + lr][ks * 16 + lq * 8];
                acc = mfma32(a, bh, acc);
            }
            const int n = n0 + nh * 32 + lr;
            #pragma unroll
            for (int r = 0; r < 16; ++r) {
                int c = (r & 3) + 8 * (r >> 2) + 4 * lq + ct * 32;
                vw[((size_t)(b * Cc + c)) * Nn + n] = (__bf16)acc[r];
            }
        }
    }
}

// ------ Kernel 2: attention, 4 waves = 2 qg x 2 key-halves, q-tile 64 --------
// grid (64, 8), 256 threads, 2 blocks/CU, 1 barrier/iter.
__global__ __launch_bounds__(256, 2) void attn_kernel(
    const float* __restrict__ x, const float* __restrict__ qw,
    const __bf16* __restrict__ khw, const __bf16* __restrict__ klw,
    const __bf16* __restrict__ vw,
    const float* __restrict__ gamma, float* __restrict__ out)
{
    const int b = blockIdx.y, n0b = blockIdx.x * 64, t = threadIdx.x;
    const int wave = t >> 6, lane = t & 63, lr = lane & 31, lq = lane >> 5;
    const int qg = wave & 1, kq = wave >> 1;
    const int kbase = kq * 2048;
    const bool lq0 = (lq == 0);

    // [kq-half][buf][c][m] bf16, 73728 B; merge region reuses it at the end.
    __shared__ __align__(16) unsigned char smem[2 * 2 * 128 * 72 * 2];
    __shared__ float lred[2][32];
    __bf16 (*vT)[2][128][72] = (__bf16 (*)[2][128][72])smem;

    // staging map (measured 0 LDS conflicts in r5/r7/r8): pair-per-row
    const int sc = t >> 1, sm = (t & 1) * 32;
    const __bf16* vbase = vw + ((size_t)(b * Cc + sc)) * Nn + sm;

    // Q frags (qw pre-scaled by log2e)
    const int nq = n0b + qg * 32 + lr;
    bf16x8 qhi, qlo;
    {
        float qa[8];
        *(float4*)&qa[0] = *(const float4*)(qw + ((size_t)b * Nn + nq) * CQ + lq * 8);
        *(float4*)&qa[4] = *(const float4*)(qw + ((size_t)b * Nn + nq) * CQ + lq * 8 + 4);
        #pragma unroll
        for (int j = 0; j < 8; ++j) { HL z = hilo(qa[j]); qhi[j] = z.h; qlo[j] = z.l; }
    }

    const __bf16* khb = khw + ((size_t)b * Nn + kbase) * CQ + lq * 8;
    const __bf16* klb = klw + ((size_t)b * Nn + kbase) * CQ + lq * 8;

    // ---- prologue: stage chunk 0 -> buf 0; prefetch chunk 1; K(0) in regs ----
    uint4 pv[2][4];
    #pragma unroll
    for (int h = 0; h < 2; ++h)
        #pragma unroll
        for (int i = 0; i < 4; ++i) pv[h][i] = *(const uint4*)(vbase + h * 2048 + 8 * i);
    #pragma unroll
    for (int h = 0; h < 2; ++h)
        #pragma unroll
        for (int i = 0; i < 4; ++i) *(uint4*)&vT[h][0][sc][sm + 8 * i] = pv[h][i];
    #pragma unroll
    for (int h = 0; h < 2; ++h)
        #pragma unroll
        for (int i = 0; i < 4; ++i) pv[h][i] = *(const uint4*)(vbase + h * 2048 + 64 + 8 * i);

    bf16x8 k0h = *(const bf16x8*)(khb + (size_t)lr * CQ);
    bf16x8 k0l = *(const bf16x8*)(klb + (size_t)lr * CQ);
    bf16x8 k1h = *(const bf16x8*)(khb + (size_t)(32 + lr) * CQ);
    bf16x8 k1l = *(const bf16x8*)(klb + (size_t)(32 + lr) * CQ);

    __syncthreads();

    f32x16 acc[4] = {{}, {}, {}, {}};
    float l_run = 0.f;

    for (int it = 0; it < 32; ++it) {
        const int p = it & 1;

        // commit staged V(it+1) -> idle buffer (readers are past last barrier)
        if (it + 1 < 32) {
            #pragma unroll
            for (int h = 0; h < 2; ++h)
                #pragma unroll
                for (int i = 0; i < 4; ++i)
                    *(uint4*)&vT[h][1 - p][sc][sm + 8 * i] = pv[h][i];
        }
        // prefetch V(it+2) into regs (clamped, branchless)
        {
            const int nc = (it + 2 < 32) ? it + 2 : 31;
            #pragma unroll
            for (int h = 0; h < 2; ++h)
                #pragma unroll
                for (int i = 0; i < 4; ++i)
                    pv[h][i] = *(const uint4*)(vbase + h * 2048 + nc * 64 + 8 * i);
        }

        // S^T = K * Q^T for 64 keys (current K regs)
        f32x16 s0 = {}, s1 = {};
        s0 = mfma32(k0h, qhi, s0); s0 = mfma32(k0l, qhi, s0); s0 = mfma32(k0h, qlo, s0);
        s1 = mfma32(k1h, qhi, s1); s1 = mfma32(k1l, qhi, s1); s1 = mfma32(k1h, qlo, s1);

        // prefetch K(it+1) (clamped)
        {
            const int nit = (it + 1 < 32) ? it + 1 : 31;
            const size_t r0 = (size_t)(nit * 64 + lr) * CQ;
            const size_t r1 = (size_t)(nit * 64 + 32 + lr) * CQ;
            bf16x8 nk0h = *(const bf16x8*)(khb + r0);
            bf16x8 nk0l = *(const bf16x8*)(klb + r0);
            bf16x8 nk1h = *(const bf16x8*)(khb + r1);
            bf16x8 nk1l = *(const bf16x8*)(klb + r1);

            // no-max softmax: p = exp2(s) (s already includes log2e via Q)
            float e0[16], e1[16];
            #pragma unroll
            for (int r = 0; r < 16; ++r) {
                e0[r] = __builtin_exp2f(s0[r]);
                e1[r] = __builtin_exp2f(s1[r]);
            }
            float csum = 0.f;
            #pragma unroll
            for (int r = 0; r < 16; ++r) csum += e0[r] + e1[r];
            l_run += csum;

            // pack to bf16 pairs (ALL indices compile-time constants)
            u32 Qk[16];
            #pragma unroll
            for (int g = 0; g < 4; ++g) {
                Qk[2 * g]         = pack2(e0[4 * g],     e0[4 * g + 1]);
                Qk[2 * g + 1]     = pack2(e0[4 * g + 2], e0[4 * g + 3]);
                Qk[8 + 2 * g]     = pack2(e1[4 * g],     e1[4 * g + 1]);
                Qk[8 + 2 * g + 1] = pack2(e1[4 * g + 2], e1[4 * g + 3]);
            }

            // quad exchange with xor-32 partner: send pre-selected payload so
            // only 8 shuffles needed. A[s]=(s>>1)*4+(s&1), B[s]=A[s]+2 — const.
            u32 rcv[8];
            #pragma unroll
            for (int s = 0; s < 8; ++s) {
                const int As = (s >> 1) * 4 + (s & 1);
                const int Bs = As + 2;
                u32 snd = lq0 ? Qk[Bs] : Qk[As];
                rcv[s] = (u32)__shfl_xor((int)snd, 32);
            }
            // pf[ks]: lq=0 -> {Qk[4ks],Qk[4ks+1],rcv[2ks],rcv[2ks+1]}
            //         lq=1 -> {rcv[2ks],rcv[2ks+1],Qk[4ks+2],Qk[4ks+3]}
            bf16x8 pf[4];
            #pragma unroll
            for (int ks = 0; ks < 4; ++ks) {
                u32x4 w;
                w[0] = lq0 ? Qk[4 * ks]     : rcv[2 * ks];
                w[1] = lq0 ? Qk[4 * ks + 1] : rcv[2 * ks + 1];
                w[2] = lq0 ? rcv[2 * ks]     : Qk[4 * ks + 2];
                w[3] = lq0 ? rcv[2 * ks + 1] : Qk[4 * ks + 3];
                pf[ks] = __builtin_bit_cast(bf16x8, w);
            }

            // O^T += V^T * P  (reads current buffer p)
            #pragma unroll
            for (int ct = 0; ct < 4; ++ct) {
                #pragma unroll
                for (int ks = 0; ks < 4; ++ks) {
                    bf16x8 va = *(const bf16x8*)&vT[kq][p][ct * 32 + lr][ks * 16 + lq * 8];
                    acc[ct] = mfma32(va, pf[ks], acc[ct]);
                }
            }

            // rotate K pipeline
            k0h = nk0h; k0l = nk0l; k1h = nk1h; k1l = nk1l;
        }

        __syncthreads();   // the only barrier per iteration
    }

    // ---- additive merge across the two key-halves (no-max => plain sums) ----
    const float l_tot = l_run + __shfl_xor(l_run, 32);
    constexpr int RP = 129;
    float* mergeO = (float*)smem;            // vT dead; reuse
    float* reg = mergeO + qg * (32 * RP);

    if (kq == 1) {
        if (lq == 0) lred[qg][lr] = l_tot;
        #pragma unroll
        for (int ct = 0; ct < 4; ++ct)
            #pragma unroll
            for (int r = 0; r < 16; ++r) {
                int c = (r & 3) + 8 * (r >> 2) + 4 * lq + 32 * ct;
                reg[lr * RP + c] = acc[ct][r];
            }
    }
    __syncthreads();
    if (kq == 0) {
        const float linv = 1.0f / (l_tot + lred[qg][lr]);
        const float gg = gamma[0];
        #pragma unroll
        for (int ct = 0; ct < 4; ++ct)
            #pragma unroll
            for (int r = 0; r < 16; ++r) {
                int c = (r & 3) + 8 * (r >> 2) + 4 * lq + 32 * ct;
                size_t idx = ((size_t)(b * Cc + c)) * Nn + nq;
                out[idx] = x[idx] + gg * (acc[ct][r] + reg[lr * RP + c]) * linv;
            }
    }
}

extern "C" void kernel_launch(void* const* d_in, const int* in_sizes, int n_in,
                              void* d_out, int out_size, void* d_ws, size_t ws_size,
                              hipStream_t stream) {
    const float* x  = (const float*)d_in[0];
    const float* Wq = (const float*)d_in[1];
    const float* Wk = (const float*)d_in[2];
    const float* Wv = (const float*)d_in[3];
    const float* gm = (const float*)d_in[4];

    float*  qw  = (float*)d_ws;                               // [B][N][16] fp32 (x log2e)
    __bf16* khw = (__bf16*)(qw + (size_t)Bb * Nn * CQ);       // [B][N][16] bf16 hi
    __bf16* klw = khw + (size_t)Bb * Nn * CQ;                 // [B][N][16] bf16 lo
    __bf16* vw  = klw + (size_t)Bb * Nn * CQ;                 // [B][C][N] bf16 (V^T)

    qkv_kernel<<<dim3(Nn / 64, Bb), 256, 0, stream>>>(x, Wq, Wk, Wv, qw, khw, klw, vw);
    attn_kernel<<<dim3(Nn / 64, Bb), 256, 0, stream>>>(x, qw, khw, klw, vw, gm,
                                                       (float*)d_out);
}